// Round 11
// baseline (129.409 us; speedup 1.0000x reference)
//
#include <hip/hip_runtime.h>
#include <hip/hip_fp16.h>
#include <math.h>

#define BATCH 8
#define NSLOT 256
#define DDIM  256
#define HID   128
#define NREL  8

typedef _Float16 half8 __attribute__((ext_vector_type(8)));
typedef float float4v __attribute__((ext_vector_type(4)));

union U8 {
  uint32_t u[4];
  _Float16 f[8];
  half8 v;
  float4 f4;
};

union H4 {
  _Float16 f[4];
  double d;
};

// d_ws: WT f16[256][256] at 0 (128 KB); W2T f16[16][128] at 512 KB.

// ---------------------------------------------------------------------------
// Kernel 0 (validated R10): WT[c][k] = (f16) Wc[k][c], Wc[k][c] = (c<128) ?
// W1[k][c] : W1[256+k][c-128]; block (0,0) also builds W2T[n][k] (zero n>=8).
// ---------------------------------------------------------------------------
__global__ __launch_bounds__(256) void wt_kernel(
    const float* __restrict__ W1, const float* __restrict__ W2,
    _Float16* __restrict__ WT, _Float16* __restrict__ W2T) {
  __shared__ float T[32][33];
  const int tx = threadIdx.x & 31;
  const int ty = threadIdx.x >> 5;
  const int c0 = blockIdx.x * 32, k0 = blockIdx.y * 32;
#pragma unroll
  for (int p = 0; p < 4; ++p) {
    const int k = k0 + ty + p * 8;
    const int c = c0 + tx;
    T[ty + p * 8][tx] = (c < HID) ? W1[(size_t)k * HID + c]
                                  : W1[(size_t)(DDIM + k) * HID + (c - HID)];
  }
  __syncthreads();
#pragma unroll
  for (int p = 0; p < 4; ++p) {
    const int cl = ty + p * 8;
    WT[(size_t)(c0 + cl) * 256 + k0 + tx] = (_Float16)T[tx][cl];
  }
  if (blockIdx.x == 0 && blockIdx.y == 0) {
#pragma unroll
    for (int p = 0; p < 8; ++p) {
      const int idx = threadIdx.x + p * 256;
      const int n = idx >> 7, k = idx & 127;
      W2T[n * 128 + k] = (n < 8) ? (_Float16)W2[k * NREL + n] : (_Float16)0.0f;
    }
  }
}

// ---------------------------------------------------------------------------
// Fused v3 (lean): block = (b, 16 i, 16 j), 2048 blocks x 256 thr (2 rounds
// of 4/CU -> round 2 overlaps round 1 tail). LDS 16.9 KB, 2 barriers,
// 48 MFMA/wave.
//  Phase 1: stage 32 slot rows (16 i + 16 j) -> f16 LDS pitch 264 (r wave-
//           uniform: r = 4p + wave).
//  Phase 2: proj. Wave w -> hid cols {2w,2w+1}*16+lo16; B-frags = WT 16-B
//           loads; P1 (i-rows) 8 MFMA + P2 (j-rows) 8 MFMA per c-tile.
//  Phase 3: barrier; P1+b1 / P2 -> aliased LDS (pitch 136); barrier.
//  Phase 4: pair (validated): wave w -> i in {4w..4w+3}; per i: 4x[ds_read
//           broadcast + pk-relu + MFMA w/ W2T frags] -> sigmoid -> stores.
// MFMA maps (HW-validated R5-R10): A[m=lane&15][k=(lane>>4)*8+u],
//  B[k=(lane>>4)*8+u][n=lane&15], D[m=(lane>>4)*4+reg][n=lane&15].
// ---------------------------------------------------------------------------
__global__ __launch_bounds__(256, 4) void fused_kernel(
    const float* __restrict__ slots, const _Float16* __restrict__ WT,
    const _Float16* __restrict__ W2T, const float* __restrict__ b1,
    const float* __restrict__ b2, float* __restrict__ out) {
  __shared__ _Float16 LB[32 * 264];   // 16,896 B
  _Float16* SLI = LB;                 // [16][264] staging i-rows
  _Float16* SLJ = LB + 16 * 264;      // [16][264] staging j-rows
  _Float16* P1L = LB;                 // [16][136] aliased after phase 2
  _Float16* P2L = LB + 16 * 136;      // [16][136]

  const int tid  = threadIdx.x;
  const int w    = tid >> 6;
  const int lane = tid & 63;
  const int lo16 = lane & 15;
  const int kg   = lane >> 4;  // 0..3

  const int b  = blockIdx.z;
  const int i0 = blockIdx.y * 16;
  const int j0 = blockIdx.x * 16;
  const float* Sb = slots + (size_t)b * NSLOT * DDIM;

  // ---- Phase 1: stage 32 rows -> f16 LDS (r = 4p + w, wave-uniform) ----
#pragma unroll
  for (int p = 0; p < 8; ++p) {
    const int idx = tid + p * 256;
    const int r  = idx >> 6;          // 0..31
    const int c4 = (idx & 63) * 4;
    const int grow = (r < 16) ? (i0 + r) : (j0 + r - 16);
    const float4 f = *(const float4*)(Sb + (size_t)grow * DDIM + c4);
    H4 h;
    h.f[0] = (_Float16)f.x; h.f[1] = (_Float16)f.y;
    h.f[2] = (_Float16)f.z; h.f[3] = (_Float16)f.w;
    *(double*)&LB[r * 264 + c4] = h.d;
  }
  __syncthreads();

  // ---- Phase 2: proj into registers ----
  float4v p1acc[2], p2acc[2];
  float b1v[2];
#pragma unroll
  for (int t = 0; t < 2; ++t) {
    p1acc[t] = (float4v){0.0f, 0.0f, 0.0f, 0.0f};
    p2acc[t] = (float4v){0.0f, 0.0f, 0.0f, 0.0f};
  }
#pragma unroll
  for (int t = 0; t < 2; ++t) {
    const int c = (2 * w + t) * 16 + lo16;  // hid col 0..127
    b1v[t] = b1[c];
    U8 bf1[8], bf2[8];
#pragma unroll
    for (int ks = 0; ks < 8; ++ks) {
      bf1[ks].f4 = *(const float4*)(WT + (size_t)c * 256 + ks * 32 + kg * 8);
      bf2[ks].f4 = *(const float4*)(WT + (size_t)(HID + c) * 256 + ks * 32 + kg * 8);
    }
#pragma unroll
    for (int ks = 0; ks < 8; ++ks) {
      U8 a;
      a.f4 = *(const float4*)&SLI[lo16 * 264 + ks * 32 + kg * 8];
      p1acc[t] = __builtin_amdgcn_mfma_f32_16x16x32_f16(a.v, bf1[ks].v, p1acc[t], 0, 0, 0);
    }
#pragma unroll
    for (int ks = 0; ks < 8; ++ks) {
      U8 a;
      a.f4 = *(const float4*)&SLJ[lo16 * 264 + ks * 32 + kg * 8];
      p2acc[t] = __builtin_amdgcn_mfma_f32_16x16x32_f16(a.v, bf2[ks].v, p2acc[t], 0, 0, 0);
    }
  }
  __syncthreads();  // staging reads complete; LB reusable

  // ---- Phase 3: write P into aliased LDS ----
#pragma unroll
  for (int t = 0; t < 2; ++t) {
    const int col = (2 * w + t) * 16 + lo16;
#pragma unroll
    for (int reg = 0; reg < 4; ++reg) {
      P1L[(kg * 4 + reg) * 136 + col] = (_Float16)(p1acc[t][reg] + b1v[t]);
      P2L[(kg * 4 + reg) * 136 + col] = (_Float16)p2acc[t][reg];
    }
  }
  __syncthreads();

  // ---- Phase 4: pair stage (validated) ----
  const int n = lo16;
  U8 w2f[4];
#pragma unroll
  for (int kq = 0; kq < 4; ++kq)
    w2f[kq].f4 = *(const float4*)(W2T + n * 128 + kq * 32 + kg * 8);
  const float b2v = (n < 8) ? b2[n] : 0.0f;

  U8 pj[4];
#pragma unroll
  for (int kq = 0; kq < 4; ++kq)
    pj[kq].f4 = *(const float4*)&P2L[n * 136 + kq * 32 + kg * 8];

#pragma unroll
  for (int ii = 0; ii < 4; ++ii) {
    const int i = w * 4 + ii;
    float4v acc = {0.0f, 0.0f, 0.0f, 0.0f};
#pragma unroll
    for (int kq = 0; kq < 4; ++kq) {
      U8 pi;
      pi.f4 = *(const float4*)&P1L[i * 136 + kq * 32 + kg * 8];  // broadcast
      U8 h;
      h.v = __builtin_elementwise_max(pj[kq].v + pi.v, (half8)(_Float16)0.0f);
      acc = __builtin_amdgcn_mfma_f32_16x16x32_f16(h.v, w2f[kq].v, acc, 0, 0, 0);
    }
    if (n < 8) {
      float* obase = out + (((size_t)b * NSLOT + (i0 + i)) * NSLOT + j0) * NREL + n;
#pragma unroll
      for (int reg = 0; reg < 4; ++reg) {
        const int jrow = kg * 4 + reg;
        const float x = acc[reg] + b2v;
        obase[jrow * NREL] = __builtin_amdgcn_rcpf(1.0f + __expf(-x));
      }
    }
  }
}

extern "C" void kernel_launch(void* const* d_in, const int* in_sizes, int n_in,
                              void* d_out, int out_size, void* d_ws, size_t ws_size,
                              hipStream_t stream) {
  const float* slots = (const float*)d_in[0];  // [8,256,256]
  const float* W1    = (const float*)d_in[1];  // [512,128]
  const float* b1    = (const float*)d_in[2];  // [128]
  const float* W2    = (const float*)d_in[3];  // [128,8]
  const float* b2    = (const float*)d_in[4];  // [8]
  float* out    = (float*)d_out;               // [8,256,256,8]
  _Float16* WT  = (_Float16*)d_ws;                         // 128 KB
  _Float16* W2T = (_Float16*)((char*)d_ws + (512 << 10));  // 4 KB

  wt_kernel<<<dim3(8, 8), 256, 0, stream>>>(W1, W2, WT, W2T);
  fused_kernel<<<dim3(NSLOT / 16, NSLOT / 16, BATCH), 256, 0, stream>>>(
      slots, WT, W2T, b1, b2, out);
}

// Round 12
// 87.631 us; speedup vs baseline: 1.4767x; 1.4767x over previous
//
#include <hip/hip_runtime.h>
#include <hip/hip_fp16.h>
#include <math.h>

#define BATCH 8
#define NSLOT 256
#define DDIM  256
#define HID   128
#define NREL  8

typedef _Float16 half8 __attribute__((ext_vector_type(8)));
typedef float float4v __attribute__((ext_vector_type(4)));

union U8 {
  uint32_t u[4];
  _Float16 f[8];
  half8 v;
  float4 f4;
};

// d_ws: WT f16[256][256] at 0 (128 KB); W2T f16[16][128] at 512 KB;
//       P f16[2048][256] at 1 MB.

// ---------------------------------------------------------------------------
// Kernel 0 (validated R10): WT[c][k] = (f16) Wc[k][c], Wc[k][c] = (c<128) ?
// W1[k][c] : W1[256+k][c-128]; block (0,0) also builds W2T[n][k] (zero n>=8).
// ---------------------------------------------------------------------------
__global__ __launch_bounds__(256) void wt_kernel(
    const float* __restrict__ W1, const float* __restrict__ W2,
    _Float16* __restrict__ WT, _Float16* __restrict__ W2T) {
  __shared__ float T[32][33];
  const int tx = threadIdx.x & 31;
  const int ty = threadIdx.x >> 5;
  const int c0 = blockIdx.x * 32, k0 = blockIdx.y * 32;
#pragma unroll
  for (int p = 0; p < 4; ++p) {
    const int k = k0 + ty + p * 8;
    const int c = c0 + tx;
    T[ty + p * 8][tx] = (c < HID) ? W1[(size_t)k * HID + c]
                                  : W1[(size_t)(DDIM + k) * HID + (c - HID)];
  }
  __syncthreads();
#pragma unroll
  for (int p = 0; p < 4; ++p) {
    const int cl = ty + p * 8;
    WT[(size_t)(c0 + cl) * 256 + k0 + tx] = (_Float16)T[tx][cl];
  }
  if (blockIdx.x == 0 && blockIdx.y == 0) {
#pragma unroll
    for (int p = 0; p < 8; ++p) {
      const int idx = threadIdx.x + p * 256;
      const int n = idx >> 7, k = idx & 127;
      W2T[n * 128 + k] = (n < 8) ? (_Float16)W2[k * NREL + n] : (_Float16)0.0f;
    }
  }
}

// ---------------------------------------------------------------------------
// projA (validated R9/R10): P computed once, one wave per 16x16 tile.
// 2048 blocks x 64 thr, no LDS/barriers.
// MFMA maps (HW-validated R5-R11): A[m=lane&15][k=(lane>>4)*8+u],
//  B[k=(lane>>4)*8+u][n=lane&15], D[m=(lane>>4)*4+reg][n=lane&15].
// ---------------------------------------------------------------------------
__global__ __launch_bounds__(64) void projA(
    const float* __restrict__ slots, const _Float16* __restrict__ WT,
    const float* __restrict__ b1, _Float16* __restrict__ P) {
  const int lane = threadIdx.x;
  const int lo16 = lane & 15;
  const int kg   = lane >> 4;
  const int row0 = blockIdx.y * 16;
  const int c    = blockIdx.x * 16 + lo16;

  U8 bf[8];
#pragma unroll
  for (int ks = 0; ks < 8; ++ks)
    bf[ks].f4 = *(const float4*)(WT + (size_t)c * 256 + ks * 32 + kg * 8);

  float4v acc = {0.0f, 0.0f, 0.0f, 0.0f};
  const float* srow = slots + (size_t)(row0 + lo16) * DDIM;
#pragma unroll
  for (int ks = 0; ks < 8; ++ks) {
    const float4 x0 = *(const float4*)(srow + ks * 32 + kg * 8);
    const float4 x1 = *(const float4*)(srow + ks * 32 + kg * 8 + 4);
    U8 a;
    a.f[0] = (_Float16)x0.x; a.f[1] = (_Float16)x0.y;
    a.f[2] = (_Float16)x0.z; a.f[3] = (_Float16)x0.w;
    a.f[4] = (_Float16)x1.x; a.f[5] = (_Float16)x1.y;
    a.f[6] = (_Float16)x1.z; a.f[7] = (_Float16)x1.w;
    acc = __builtin_amdgcn_mfma_f32_16x16x32_f16(a.v, bf[ks].v, acc, 0, 0, 0);
  }

  const float bias = (c < HID) ? b1[c] : 0.0f;
#pragma unroll
  for (int reg = 0; reg < 4; ++reg)
    P[(size_t)(row0 + kg * 4 + reg) * 256 + c] = (_Float16)(acc[reg] + bias);
}

// ---------------------------------------------------------------------------
// pair v5: ZERO LDS, ZERO barriers, 1 wave per block (projA philosophy —
// the only structure class that has run near-model all session).
// Wave = (b, 16 i, 16 j). Per wave: pj[4] + w2f[4] in regs; per i: 4
// same-address 16-B broadcast loads of P1[i] (L1-served, manually
// double-buffered one i ahead) + pk-relu + 4 MFMA -> sigmoid -> stores.
// 2048 blocks = 8 waves/SIMD; nothing convoys.
// ---------------------------------------------------------------------------
__global__ __launch_bounds__(64) void pair_kernel(
    const _Float16* __restrict__ P, const _Float16* __restrict__ W2T,
    const float* __restrict__ b2, float* __restrict__ out) {
  const int lane = threadIdx.x;
  const int n    = lane & 15;   // rel col (store) / j within tile (pj load)
  const int kg   = lane >> 4;

  const int b  = blockIdx.z;
  const int i0 = blockIdx.y * 16;
  const int j0 = blockIdx.x * 16;
  const _Float16* Pb = P + (size_t)b * NSLOT * 256;

  // Pj A-side fragments (j = j0+n), held across all 16 i's.
  U8 pj[4];
#pragma unroll
  for (int kq = 0; kq < 4; ++kq)
    pj[kq].f4 = *(const float4*)(Pb + (size_t)(j0 + n) * 256 + HID + kq * 32 + kg * 8);

  // W2T B-fragments (zero-padded cols n>=8).
  U8 w2f[4];
#pragma unroll
  for (int kq = 0; kq < 4; ++kq)
    w2f[kq].f4 = *(const float4*)(W2T + n * 128 + kq * 32 + kg * 8);

  const float b2v = (n < 8) ? b2[n] : 0.0f;

  // Manual 1-deep pipeline on the Pi broadcast loads.
  U8 pic[4], pin[4];
#pragma unroll
  for (int kq = 0; kq < 4; ++kq)
    pic[kq].f4 = *(const float4*)(Pb + (size_t)i0 * 256 + kq * 32 + kg * 8);

  for (int i = 0; i < 16; ++i) {
    if (i < 15) {
#pragma unroll
      for (int kq = 0; kq < 4; ++kq)
        pin[kq].f4 =
            *(const float4*)(Pb + (size_t)(i0 + i + 1) * 256 + kq * 32 + kg * 8);
    }
    float4v acc = {0.0f, 0.0f, 0.0f, 0.0f};
#pragma unroll
    for (int kq = 0; kq < 4; ++kq) {
      U8 h;
      h.v = __builtin_elementwise_max(pj[kq].v + pic[kq].v, (half8)(_Float16)0.0f);
      acc = __builtin_amdgcn_mfma_f32_16x16x32_f16(h.v, w2f[kq].v, acc, 0, 0, 0);
    }
    if (n < 8) {
      float* obase = out + (((size_t)b * NSLOT + (i0 + i)) * NSLOT + j0) * NREL + n;
#pragma unroll
      for (int reg = 0; reg < 4; ++reg) {
        const int jrow = kg * 4 + reg;
        const float x = acc[reg] + b2v;
        obase[jrow * NREL] = __builtin_amdgcn_rcpf(1.0f + __expf(-x));
      }
    }
#pragma unroll
    for (int kq = 0; kq < 4; ++kq) pic[kq] = pin[kq];
  }
}

extern "C" void kernel_launch(void* const* d_in, const int* in_sizes, int n_in,
                              void* d_out, int out_size, void* d_ws, size_t ws_size,
                              hipStream_t stream) {
  const float* slots = (const float*)d_in[0];  // [8,256,256]
  const float* W1    = (const float*)d_in[1];  // [512,128]
  const float* b1    = (const float*)d_in[2];  // [128]
  const float* W2    = (const float*)d_in[3];  // [128,8]
  const float* b2    = (const float*)d_in[4];  // [8]
  float* out    = (float*)d_out;               // [8,256,256,8]
  _Float16* WT  = (_Float16*)d_ws;                         // 128 KB
  _Float16* W2T = (_Float16*)((char*)d_ws + (512 << 10));  // 4 KB
  _Float16* P   = (_Float16*)((char*)d_ws + (1 << 20));    // 1 MB

  wt_kernel<<<dim3(8, 8), 256, 0, stream>>>(W1, W2, WT, W2T);
  projA<<<dim3(16, 128), 64, 0, stream>>>(slots, WT, b1, P);
  pair_kernel<<<dim3(16, 16, BATCH), 64, 0, stream>>>(P, W2T, b2, out);
}

// Round 13
// 83.959 us; speedup vs baseline: 1.5413x; 1.0437x over previous
//
#include <hip/hip_runtime.h>
#include <hip/hip_fp16.h>
#include <math.h>

#define BATCH 8
#define NSLOT 256
#define DDIM  256
#define HID   128
#define NREL  8

typedef _Float16 half8 __attribute__((ext_vector_type(8)));
typedef float float4v __attribute__((ext_vector_type(4)));

union U8 {
  uint32_t u[4];
  _Float16 f[8];
  half8 v;
  float4 f4;
};

// d_ws layout: WT f16[256][256] at 0 (128 KB); W2T f16[16][128] at 512 KB;
//              P f16[2048][256] at 1 MB.
// R13 = exact restore of R10 (session best, 84.8 us): barrier-light 3-kernel
// chain. Fused variants (R7/R8/R11) all regressed 3-10x over model; this
// split structure is the only one that runs near its pipe model.

// ---------------------------------------------------------------------------
// Kernel 0 (validated): WT[c][k] = (f16) Wc[k][c], Wc[k][c] = (c<128) ?
// W1[k][c] : W1[256+k][c-128]; block (0,0) also builds W2T[n][k] (zero n>=8).
// ---------------------------------------------------------------------------
__global__ __launch_bounds__(256) void wt_kernel(
    const float* __restrict__ W1, const float* __restrict__ W2,
    _Float16* __restrict__ WT, _Float16* __restrict__ W2T) {
  __shared__ float T[32][33];
  const int tx = threadIdx.x & 31;
  const int ty = threadIdx.x >> 5;
  const int c0 = blockIdx.x * 32, k0 = blockIdx.y * 32;
#pragma unroll
  for (int p = 0; p < 4; ++p) {
    const int k = k0 + ty + p * 8;
    const int c = c0 + tx;
    T[ty + p * 8][tx] = (c < HID) ? W1[(size_t)k * HID + c]
                                  : W1[(size_t)(DDIM + k) * HID + (c - HID)];
  }
  __syncthreads();
#pragma unroll
  for (int p = 0; p < 4; ++p) {
    const int cl = ty + p * 8;
    WT[(size_t)(c0 + cl) * 256 + k0 + tx] = (_Float16)T[tx][cl];
  }
  if (blockIdx.x == 0 && blockIdx.y == 0) {
#pragma unroll
    for (int p = 0; p < 8; ++p) {
      const int idx = threadIdx.x + p * 256;
      const int n = idx >> 7, k = idx & 127;
      W2T[n * 128 + k] = (n < 8) ? (_Float16)W2[k * NREL + n] : (_Float16)0.0f;
    }
  }
}

// ---------------------------------------------------------------------------
// projA (validated R9/R10): P computed once, one wave per 16x16 tile.
// 2048 blocks x 64 thr, no LDS/barriers. 16 slots float4 loads (cvt f16) +
// 8 WT B-frags + 8 MFMA + bias + stores.
// MFMA maps (HW-validated R5-R12): A[m=lane&15][k=(lane>>4)*8+u],
//  B[k=(lane>>4)*8+u][n=lane&15], D[m=(lane>>4)*4+reg][n=lane&15].
// ---------------------------------------------------------------------------
__global__ __launch_bounds__(64) void projA(
    const float* __restrict__ slots, const _Float16* __restrict__ WT,
    const float* __restrict__ b1, _Float16* __restrict__ P) {
  const int lane = threadIdx.x;
  const int lo16 = lane & 15;
  const int kg   = lane >> 4;
  const int row0 = blockIdx.y * 16;
  const int c    = blockIdx.x * 16 + lo16;

  U8 bf[8];
#pragma unroll
  for (int ks = 0; ks < 8; ++ks)
    bf[ks].f4 = *(const float4*)(WT + (size_t)c * 256 + ks * 32 + kg * 8);

  float4v acc = {0.0f, 0.0f, 0.0f, 0.0f};
  const float* srow = slots + (size_t)(row0 + lo16) * DDIM;
#pragma unroll
  for (int ks = 0; ks < 8; ++ks) {
    const float4 x0 = *(const float4*)(srow + ks * 32 + kg * 8);
    const float4 x1 = *(const float4*)(srow + ks * 32 + kg * 8 + 4);
    U8 a;
    a.f[0] = (_Float16)x0.x; a.f[1] = (_Float16)x0.y;
    a.f[2] = (_Float16)x0.z; a.f[3] = (_Float16)x0.w;
    a.f[4] = (_Float16)x1.x; a.f[5] = (_Float16)x1.y;
    a.f[6] = (_Float16)x1.z; a.f[7] = (_Float16)x1.w;
    acc = __builtin_amdgcn_mfma_f32_16x16x32_f16(a.v, bf[ks].v, acc, 0, 0, 0);
  }

  const float bias = (c < HID) ? b1[c] : 0.0f;
#pragma unroll
  for (int reg = 0; reg < 4; ++reg)
    P[(size_t)(row0 + kg * 4 + reg) * 256 + c] = (_Float16)(acc[reg] + bias);
}

// ---------------------------------------------------------------------------
// pair v4 (validated R10, session-best): i-tile 8, 1024 blocks x 256 thr
// (4 waves/SIMD), one tiny Pi LDS stage + one barrier, W2T 16-B B-frags.
// out[b,i,j,r] = sigmoid( sum_k relu(P[b,i,k]+P[b,j,128+k]) * W2[k,r] + b2[r] )
// ---------------------------------------------------------------------------
__global__ __launch_bounds__(256) void pair_kernel(
    const _Float16* __restrict__ P, const _Float16* __restrict__ W2T,
    const float* __restrict__ b2, float* __restrict__ out) {
  __shared__ uint32_t PiL[8 * 68];

  const int tid  = threadIdx.x;
  const int w    = tid >> 6;
  const int lane = tid & 63;
  const int n    = lane & 15;
  const int kg   = lane >> 4;

  const int b   = blockIdx.z;
  const int i0  = blockIdx.y * 8;
  const int j0  = blockIdx.x * 64 + w * 16;
  const _Float16* Pb = P + (size_t)b * NSLOT * 256;

  if (tid < 128) {  // stage Pi: 8 rows x 128 f16
    const int r  = tid >> 4;
    const int ch = tid & 15;
    const float4 t = *(const float4*)(Pb + (size_t)(i0 + r) * 256 + ch * 8);
    *(float4*)&PiL[r * 68 + ch * 4] = t;
  }

  U8 w2f[4];
#pragma unroll
  for (int kq = 0; kq < 4; ++kq)
    w2f[kq].f4 = *(const float4*)(W2T + n * 128 + kq * 32 + kg * 8);

  const float b2v = (n < 8) ? b2[n] : 0.0f;

  U8 pj[4];
#pragma unroll
  for (int kq = 0; kq < 4; ++kq)
    pj[kq].f4 = *(const float4*)(Pb + (size_t)(j0 + n) * 256 + HID + kq * 32 + kg * 8);

  __syncthreads();

#pragma unroll
  for (int i = 0; i < 8; ++i) {
    float4v acc = {0.0f, 0.0f, 0.0f, 0.0f};
#pragma unroll
    for (int kq = 0; kq < 4; ++kq) {
      U8 pi;
      pi.f4 = *(const float4*)&PiL[i * 68 + kq * 16 + kg * 4];  // broadcast
      U8 h;
      h.v = __builtin_elementwise_max(pj[kq].v + pi.v, (half8)(_Float16)0.0f);
      acc = __builtin_amdgcn_mfma_f32_16x16x32_f16(h.v, w2f[kq].v, acc, 0, 0, 0);
    }
    if (n < 8) {
      float* obase = out + (((size_t)b * NSLOT + (i0 + i)) * NSLOT + j0) * NREL + n;
#pragma unroll
      for (int reg = 0; reg < 4; ++reg) {
        const int jrow = kg * 4 + reg;
        const float x = acc[reg] + b2v;
        obase[jrow * NREL] = __builtin_amdgcn_rcpf(1.0f + __expf(-x));
      }
    }
  }
}

extern "C" void kernel_launch(void* const* d_in, const int* in_sizes, int n_in,
                              void* d_out, int out_size, void* d_ws, size_t ws_size,
                              hipStream_t stream) {
  const float* slots = (const float*)d_in[0];  // [8,256,256]
  const float* W1    = (const float*)d_in[1];  // [512,128]
  const float* b1    = (const float*)d_in[2];  // [128]
  const float* W2    = (const float*)d_in[3];  // [128,8]
  const float* b2    = (const float*)d_in[4];  // [8]
  float* out    = (float*)d_out;               // [8,256,256,8]
  _Float16* WT  = (_Float16*)d_ws;                         // 128 KB
  _Float16* W2T = (_Float16*)((char*)d_ws + (512 << 10));  // 4 KB
  _Float16* P   = (_Float16*)((char*)d_ws + (1 << 20));    // 1 MB

  wt_kernel<<<dim3(8, 8), 256, 0, stream>>>(W1, W2, WT, W2T);
  projA<<<dim3(16, 128), 64, 0, stream>>>(slots, WT, b1, P);
  pair_kernel<<<dim3(NSLOT / 64, NSLOT / 8, BATCH), 256, 0, stream>>>(P, W2T, b2, out);
}